// Round 17
// baseline (93.468 us; speedup 1.0000x reference)
//
#include <hip/hip_runtime.h>
#include <hip/hip_fp16.h>

#define IN_DIM 256
#define HID 128
#define ELLW 16
#define OVF_CAP 32768

using bf16x8 = __attribute__((ext_vector_type(8))) short;
using f32x4 = __attribute__((ext_vector_type(4))) float;

struct h8 { __half2 a, b, c, d; };  // 16B = 8 halves

__device__ __forceinline__ unsigned short f2bf(float f) {
    unsigned u = __float_as_uint(f);
    u += 0x7fffu + ((u >> 16) & 1u);  // RNE (inputs finite)
    return (unsigned short)(u >> 16);
}

// ---- DPP row_ror rotate-reductions over 16-lane groups (VALU pipe) ----
template <int CTRL>
__device__ __forceinline__ float dpp_rot(float x) {
    return __int_as_float(
        __builtin_amdgcn_update_dpp(0, __float_as_int(x), CTRL, 0xf, 0xf, false));
}
__device__ __forceinline__ float rsum16(float x) {
    x += dpp_rot<0x121>(x);
    x += dpp_rot<0x122>(x);
    x += dpp_rot<0x124>(x);
    x += dpp_rot<0x128>(x);
    return x;
}
__device__ __forceinline__ float rmax16(float x) {
    x = fmaxf(x, dpp_rot<0x121>(x));
    x = fmaxf(x, dpp_rot<0x122>(x));
    x = fmaxf(x, dpp_rot<0x124>(x));
    x = fmaxf(x, dpp_rot<0x128>(x));
    return x;
}

__device__ __forceinline__ float lrelu(float t) { return t > 0.f ? t : 0.2f * t; }

__device__ __forceinline__ void accum8(f32x4& a0, f32x4& a1, float a, const h8& hv) {
    const float2 f0 = __half22float2(hv.a);
    const float2 f1 = __half22float2(hv.b);
    const float2 f2 = __half22float2(hv.c);
    const float2 f3 = __half22float2(hv.d);
    a0[0] += a * f0.x; a0[1] += a * f0.y;
    a0[2] += a * f1.x; a0[3] += a * f1.y;
    a1[0] += a * f2.x; a1[1] += a * f2.y;
    a1[2] += a * f3.x; a1[3] += a * f3.y;
}

// epilogue: q = rsum16( relu(acc+bias)·dvec )
__device__ __forceinline__ float epilogue16(const f32x4& a0, const f32x4& a1,
                                            const float* __restrict__ bias,
                                            const float* __restrict__ dvec, int sl) {
    const f32x4 bb0 = *reinterpret_cast<const f32x4*>(bias + sl * 8);
    const f32x4 bb1 = *reinterpret_cast<const f32x4*>(bias + sl * 8 + 4);
    const f32x4 d0 = *reinterpret_cast<const f32x4*>(dvec + sl * 8);
    const f32x4 d1 = *reinterpret_cast<const f32x4*>(dvec + sl * 8 + 4);
    float q = 0.f;
#pragma unroll
    for (int i = 0; i < 4; ++i) {
        q += fmaxf(a0[i] + bb0[i], 0.f) * d0[i];
        q += fmaxf(a1[i] + bb1[i], 0.f) * d1[i];
    }
    return rsum16(q);
}

// ====== K1: setup: collapsed weights + bcomb + wd/v2/c2 + zero deg/ell ======
__global__ __launch_bounds__(256) void setup_k(const float* __restrict__ lin_W,
                                               const float* __restrict__ lin_b,
                                               const float* __restrict__ conv_Ws,
                                               const float* __restrict__ Wd,
                                               const float* __restrict__ adv,
                                               short* __restrict__ wt0,
                                               short* __restrict__ wt1,
                                               float* __restrict__ bc,   // [2][128]
                                               float* __restrict__ wd_out,
                                               float* __restrict__ v2,
                                               float* __restrict__ c2,
                                               int* __restrict__ deg,
                                               int* __restrict__ ell,
                                               int* __restrict__ ovf_cnt, int NS, int zd) {
    const int b = blockIdx.x;
    if (b < 256) {
        // Wcomb[l][k][n] = sum_m linW0[k][m] * Wc_l[m][n]; store bf16 ELL-layout
        const int idx = b * 256 + threadIdx.x;  // [0, 65536)
        const int l = idx >> 15;
        const int rem = idx & 32767;
        const int k = rem >> 7;
        const int n = rem & 127;
        const float* lw = lin_W + (size_t)k * HID;
        const float* cw = conv_Ws + (size_t)(l * 5) * HID * HID + n;
        float s = 0.f;
#pragma unroll 4
        for (int m = 0; m < HID; ++m) s += lw[m] * cw[(size_t)m * HID];
        short* wt = l ? wt1 : wt0;
        wt[((k >> 3) << 10) + (n << 3) + (k & 7)] = (short)f2bf(s);
    } else if (b == 256) {
        // bcomb[l][n] = sum_m lin_b0[m] * Wc_l[m][n]
        const int t = threadIdx.x;
        const int l = t >> 7;
        const int n = t & 127;
        const float* cw = conv_Ws + (size_t)(l * 5) * HID * HID + n;
        float s = 0.f;
#pragma unroll 4
        for (int m = 0; m < HID; ++m) s += lin_b[m] * cw[(size_t)m * HID];
        bc[t] = s;
        if (t == 0) ovf_cnt[0] = 0;
    } else if (b == 257) {
        __shared__ float wd1s[HID];
        const int t = threadIdx.x;
        const int l = t >> 7, j = t & 127;
        const float* w = Wd + ((size_t)(l * 5) * HID + j) * HID;
        const float* a = adv + (size_t)(l * 5) * HID;
        float s = 0.f;
        for (int k = 0; k < HID; k += 4) {
            const float4 wv = *reinterpret_cast<const float4*>(w + k);
            const float4 av = *reinterpret_cast<const float4*>(a + k);
            s += wv.x * av.x + wv.y * av.y + wv.z * av.z + wv.w * av.w;
        }
        wd_out[t] = s;
        if (l == 0) wd1s[j] = s;
        __syncthreads();
        const float* wr = lin_W + 2 * (size_t)IN_DIM * HID + (size_t)t * HID;
        float p = 0.f;
        for (int k = 0; k < HID; k += 4) {
            const float4 wv = *reinterpret_cast<const float4*>(wr + k);
            p += wv.x * wd1s[k] + wv.y * wd1s[k + 1] + wv.z * wd1s[k + 2] +
                 wv.w * wd1s[k + 3];
        }
        v2[t] = p;
        if (t == 0) {
            const float* br = lin_b + 2 * HID;
            float q = 0.f;
            for (int k = 0; k < HID; ++k) q += br[k] * wd1s[k];
            c2[0] = q;
        }
    } else if (b < 258 + zd) {
        const int i4 = ((b - 258) * 256 + threadIdx.x) * 4;
        if (i4 + 4 <= NS) {
            *reinterpret_cast<int4*>(deg + i4) = make_int4(0, 0, 0, 0);
        } else {
            for (int i = i4; i < NS; ++i) deg[i] = 0;
        }
    } else {
        const int total = NS * ELLW;
        const int i4 = ((b - 258 - zd) * 256 + threadIdx.x) * 4;
        if (i4 + 4 <= total) *reinterpret_cast<int4*>(ell + i4) = make_int4(0, 0, 0, 0);
    }
}

// ====== K2: per-layer GEMM, FULL A-unroll (one latency wait per block) ======
// hs layout (half idx): row*256 + j*32 + (m16>>3)*16 + l*8 + (m16&7)
__global__ __launch_bounds__(256, 2) void gemm_k(const float* __restrict__ A,
                                                 const short* __restrict__ Wt0,
                                                 const short* __restrict__ Wt1,
                                                 const float* __restrict__ bc,
                                                 __half* __restrict__ hs,
                                                 float* __restrict__ as12,
                                                 const float* __restrict__ a1v,
                                                 const float* __restrict__ a2v, int N) {
    const int l = blockIdx.x & 1;
    const int bid = blockIdx.x >> 1;
    const short* Wt = l ? Wt1 : Wt0;
    const float* av = l ? a2v : a1v;
    const int tid = threadIdx.x;
    const int w = tid >> 6;
    const int lane = tid & 63;
    const int m16 = lane & 15;
    const int kg = lane >> 4;

    const int arow = bid * 64 + w * 16 + m16;
    const bool ok = arow < N;

    // ---- preload the lane's ENTIRE A slice: 16 float4 (256B), one wait ----
    float4 a_reg[16];
    if (ok) {
        const float* ap = A + (size_t)arow * IN_DIM + kg * 8;
#pragma unroll
        for (int kk = 0; kk < 8; ++kk) {
            a_reg[2 * kk] = *reinterpret_cast<const float4*>(ap + kk * 32);
            a_reg[2 * kk + 1] = *reinterpret_cast<const float4*>(ap + kk * 32 + 4);
        }
    } else {
#pragma unroll
        for (int i = 0; i < 16; ++i) a_reg[i] = make_float4(0.f, 0.f, 0.f, 0.f);
    }
    __builtin_amdgcn_sched_barrier(0);  // keep loads batched above compute

    f32x4 acc[8];
#pragma unroll
    for (int j = 0; j < 8; ++j) acc[j] = (f32x4){0.f, 0.f, 0.f, 0.f};

#pragma unroll
    for (int kk = 0; kk < 8; ++kk) {
        const float4 f0 = a_reg[2 * kk];
        const float4 f1 = a_reg[2 * kk + 1];
        bf16x8 af;
        af[0] = (short)f2bf(f0.x); af[1] = (short)f2bf(f0.y);
        af[2] = (short)f2bf(f0.z); af[3] = (short)f2bf(f0.w);
        af[4] = (short)f2bf(f1.x); af[5] = (short)f2bf(f1.y);
        af[6] = (short)f2bf(f1.z); af[7] = (short)f2bf(f1.w);
        const short* bbase = Wt + (((kk << 2) + kg) << 10);  // k0 = kk*32
#pragma unroll
        for (int j = 0; j < 8; ++j) {
            const bf16x8 bf = *reinterpret_cast<const bf16x8*>(bbase + ((j * 16 + m16) << 3));
            acc[j] = __builtin_amdgcn_mfma_f32_16x16x32_bf16(af, bf, acc[j], 0, 0, 0);
        }
    }

    const int rbase = bid * 64 + w * 16 + kg * 4;
    float p[4] = {0.f, 0.f, 0.f, 0.f};
#pragma unroll
    for (int j = 0; j < 8; ++j) {
        const int col = j * 16 + m16;
        const float bv = bc[l * 128 + col];
        const float a = av[col];
        const int so = j * 32 + ((m16 >> 3) << 4) + (m16 & 7) + l * 8;
#pragma unroll
        for (int r = 0; r < 4; ++r) {
            const int row = rbase + r;
            const float v = acc[j][r] + bv;
            if (row < N) hs[(size_t)row * 256 + so] = __float2half(v);
            p[r] += v * a;
        }
    }
#pragma unroll
    for (int r = 0; r < 4; ++r) p[r] = rsum16(p[r]);
    if (m16 == 0)
#pragma unroll
        for (int r = 0; r < 4; ++r) {
            const int row = rbase + r;
            if (row < N) as12[2 * (size_t)row + l] = p[r];
        }
}

// ====== K3: misc: ad1 matvec + ELL build (low VGPR, stream/atomic-bound) ======
__global__ __launch_bounds__(256) void misc_k(const int* __restrict__ src,
                                              const int* __restrict__ dst, int E,
                                              int* __restrict__ deg, int* __restrict__ ell,
                                              int2* __restrict__ ovf,
                                              int* __restrict__ ovf_cnt,
                                              const float* __restrict__ x_span,
                                              const float* __restrict__ v2,
                                              const float* __restrict__ c2,
                                              float* __restrict__ ad1_out, int NS, int ab) {
    const int b = (int)blockIdx.x;
    if (b < ab) {
        // ---- ad1 matvec: 16 lanes per SPAN row ----
        const int idx = b * 256 + threadIdx.x;
        const int row = idx >> 4;
        const int sl = threadIdx.x & 15;
        if (row >= NS) return;
        const float* xr = x_span + (size_t)row * IN_DIM + sl * 16;
        const float* vr = v2 + sl * 16;
        float p = 0.f;
#pragma unroll
        for (int i = 0; i < 4; ++i) {
            const float4 xv = *reinterpret_cast<const float4*>(xr + i * 4);
            const float4 vv = *reinterpret_cast<const float4*>(vr + i * 4);
            p += xv.x * vv.x + xv.y * vv.y + xv.z * vv.z + xv.w * vv.w;
        }
        p = rsum16(p);
        if (sl == 0) ad1_out[row] = p + c2[0];
        return;
    }
    // ---- ELL build (edge-parallel) ----
    const int e = (b - ab) * 256 + threadIdx.x;
    if (e < E) {
        const int d = dst[e], s = src[e];
        const int pos = atomicAdd(deg + d, 1);
        if (pos < ELLW) {
            ell[(size_t)d * ELLW + pos] = s;
        } else {
            const int oi = atomicAdd(ovf_cnt, 1);
            if (oi < OVF_CAP) ovf[oi] = make_int2(d, s);
        }
    }
}

// ====== K4: fused 2-layer GAT — one wave/row, unconditional 4-round gather ======
__global__ __launch_bounds__(256, 3) void gat_fused_k(
    const int* __restrict__ deg_arr, const int* __restrict__ ell,
    const int2* __restrict__ ovf, const int* __restrict__ ovf_cnt_p,
    const float* __restrict__ ad1_arr, const float2* __restrict__ as12,
    const __half* __restrict__ hs, const float* __restrict__ b1,
    const float* __restrict__ wd2v, const float* __restrict__ b2,
    const float* __restrict__ outW, const float* __restrict__ outb,
    float* __restrict__ out, int Ndst) {
    const int row = (blockIdx.x * blockDim.x + threadIdx.x) >> 6;
    const int lane = threadIdx.x & 63;
    const int sl = lane & 15;
    const int eg = lane >> 4;
    if (row >= Ndst) return;  // wave-uniform

    // metadata loads — deg/ell/ad1 independent, issue together (ell zero-padded)
    const int deg = deg_arr[row];
    const int ce = ell[(size_t)row * ELLW + sl];
    const float ad1 = ad1_arr[row];
    const float2 asv = as12[ce];

    if (deg <= ELLW) {
        // ===== layer-1 softmax (no max-shift; |score| small, exp safe) =====
        const float ex1 = (sl < deg) ? __expf(lrelu(asv.x + ad1)) : 0.f;
        const float al1 = ex1 / (rsum16(ex1) + 1e-16f);

        // ===== gather: 4 UNCONDITIONAL rounds (padding: s=0 hot line, alpha=0) ====
        f32x4 a0 = {0.f, 0.f, 0.f, 0.f}, a1 = {0.f, 0.f, 0.f, 0.f};
        h8 h2s[4];
#pragma unroll
        for (int r = 0; r < 4; ++r) {
            const int e = r * 4 + eg;               // 0..15
            const int s = __shfl(ce, e, 64);        // address needs only ce
            const float a = __shfl(al1, e, 64);     // 0 for e >= deg
            const __half* hb = hs + (size_t)s * 256 + sl * 16;
            const h8 hv1 = *reinterpret_cast<const h8*>(hb);
            h2s[r] = *reinterpret_cast<const h8*>(hb + 8);
            accum8(a0, a1, a, hv1);
        }
#pragma unroll
        for (int i = 0; i < 4; ++i) {
            a0[i] += __shfl_xor(a0[i], 16, 64);
            a0[i] += __shfl_xor(a0[i], 32, 64);
            a1[i] += __shfl_xor(a1[i], 16, 64);
            a1[i] += __shfl_xor(a1[i], 32, 64);
        }
        const float ad2 = epilogue16(a0, a1, b1, wd2v, sl);

        // ===== layer 2 (h2 already in registers) =====
        const float ex2 = (sl < deg) ? __expf(lrelu(asv.y + ad2)) : 0.f;
        const float al2 = ex2 / (rsum16(ex2) + 1e-16f);

        f32x4 b0 = {0.f, 0.f, 0.f, 0.f}, b1v = {0.f, 0.f, 0.f, 0.f};
#pragma unroll
        for (int r = 0; r < 4; ++r) {
            const float a = __shfl(al2, r * 4 + eg, 64);
            accum8(b0, b1v, a, h2s[r]);
        }
#pragma unroll
        for (int i = 0; i < 4; ++i) {
            b0[i] += __shfl_xor(b0[i], 16, 64);
            b0[i] += __shfl_xor(b0[i], 32, 64);
            b1v[i] += __shfl_xor(b1v[i], 16, 64);
            b1v[i] += __shfl_xor(b1v[i], 32, 64);
        }
        const float q = epilogue16(b0, b1v, b2, outW, sl);
        if (lane == 0) out[row] = q + outb[0];
    } else {
        // ===== general path (deg > 16, ~1e-4 of rows): eg==0 accumulates =====
        int oc = *ovf_cnt_p;
        if (oc > OVF_CAP) oc = OVF_CAP;
        float ad = ad1;
#pragma unroll
        for (int layer = 0; layer < 2; ++layer) {
            const float ac = layer ? asv.y : asv.x;
            const int ho = layer ? 8 : 0;
            const float* bias = layer ? b2 : b1;
            const float* dvec = layer ? outW : wd2v;

            float te = lrelu(ac + ad);
            float m = rmax16(te);
            for (int i = 0; i < oc; ++i) {
                const int2 o = ovf[i];
                if (o.x == row) {
                    const float2 oas = as12[o.y];
                    m = fmaxf(m, lrelu((layer ? oas.y : oas.x) + ad));
                }
            }
            const float ex = __expf(te - m);
            float dsum = rsum16(ex);
            for (int i = 0; i < oc; ++i) {
                const int2 o = ovf[i];
                if (o.x == row) {
                    const float2 oas = as12[o.y];
                    dsum += __expf(lrelu((layer ? oas.y : oas.x) + ad) - m);
                }
            }
            const float inv = 1.f / (dsum + 1e-16f);
            const float al = ex * inv;

            f32x4 acc0 = {0.f, 0.f, 0.f, 0.f}, acc1 = {0.f, 0.f, 0.f, 0.f};
            for (int i = 0; i < 16; ++i) {
                const int s = __shfl(ce, i, 64);
                float a = __shfl(al, i, 64);
                if (eg != 0) a = 0.f;
                const h8 hv =
                    *reinterpret_cast<const h8*>(hs + (size_t)s * 256 + sl * 16 + ho);
                accum8(acc0, acc1, a, hv);
            }
            for (int i = 0; i < oc; ++i) {
                const int2 o = ovf[i];
                if (o.x == row && eg == 0) {
                    const float2 oas = as12[o.y];
                    const float a = __expf(lrelu((layer ? oas.y : oas.x) + ad) - m) * inv;
                    const h8 hv =
                        *reinterpret_cast<const h8*>(hs + (size_t)o.y * 256 + sl * 16 + ho);
                    accum8(acc0, acc1, a, hv);
                }
            }
#pragma unroll
            for (int i = 0; i < 4; ++i) {
                acc0[i] += __shfl_xor(acc0[i], 16, 64);
                acc0[i] += __shfl_xor(acc0[i], 32, 64);
                acc1[i] += __shfl_xor(acc1[i], 16, 64);
                acc1[i] += __shfl_xor(acc1[i], 32, 64);
            }
            const float q = epilogue16(acc0, acc1, bias, dvec, sl);
            if (layer == 0) {
                ad = q;
            } else if (lane == 0) {
                out[row] = q + outb[0];
            }
        }
    }
}

extern "C" void kernel_launch(void* const* d_in, const int* in_sizes, int n_in,
                              void* d_out, int out_size, void* d_ws, size_t ws_size,
                              hipStream_t stream) {
    // Live dataflow: out = relu(gat2)·outW + outb over QENT->SPAN only (see R4/R5).
    const float* x_qent = (const float*)d_in[0];
    const float* x_span = (const float*)d_in[2];
    const int* e_qs = (const int*)d_in[4];  // [2][E]
    const float* lin_W = (const float*)d_in[9];
    const float* lin_b = (const float*)d_in[10];
    const float* conv_Ws = (const float*)d_in[11];
    const float* conv_Wd = (const float*)d_in[12];
    const float* conv_as = (const float*)d_in[13];
    const float* conv_ad = (const float*)d_in[14];
    const float* conv_b = (const float*)d_in[15];
    const float* out_W = (const float*)d_in[16];
    const float* out_b = (const float*)d_in[17];

    const int NQ = in_sizes[0] / IN_DIM;
    const int NS = in_sizes[2] / IN_DIM;
    const int E = in_sizes[4] / 2;
    const int* srcp = e_qs;
    const int* dstp = e_qs + E;
    (void)n_in; (void)out_size;

    // ---- workspace carve (16B-aligned slots) ----
    float* ws = (float*)d_ws;
    size_t off = 0;
    auto alloc = [&](size_t n) {
        n = (n + 3) & ~(size_t)3;
        float* p = ws + off;
        off += n;
        return p;
    };
    __half* hs = (__half*)alloc((size_t)NQ * 128);  // fp16 [NQ][256], layer-interleaved
    float* as12 = alloc(2 * (size_t)NQ);            // float2-interleaved {as1,as2}
    float* ad1 = alloc(NS);
    float* wd2 = alloc(2 * HID);
    float* v2 = alloc(IN_DIM);
    float* c2 = alloc(1);
    float* bc = alloc(2 * HID);
    int* deg = (int*)alloc(NS);
    int* ell = (int*)alloc((size_t)NS * ELLW);
    int2* ovf = (int2*)alloc(2 * OVF_CAP);
    int* ovf_cnt = (int*)alloc(1);
    short* wt0 = (short*)alloc(IN_DIM * HID / 2);
    short* wt1 = (short*)alloc(IN_DIM * HID / 2);
    (void)ws_size;

    // K1: setup (collapsed weights + bcomb + wd/v2/c2 + zero deg/ell/ovf_cnt)
    const int zd = (NS + 1023) / 1024;
    const int ze = (NS * ELLW + 1023) / 1024;
    setup_k<<<dim3(258 + zd + ze), dim3(256), 0, stream>>>(
        lin_W, lin_b, conv_Ws, conv_Wd, conv_ad, wt0, wt1, bc, wd2, v2, c2, deg, ell,
        ovf_cnt, NS, zd);

    // K2: per-layer GEMM (full A-unroll, high VGPR, few fast blocks)
    const int gb2 = 2 * ((NQ + 63) / 64);
    gemm_k<<<dim3(gb2), dim3(256), 0, stream>>>(x_qent, wt0, wt1, bc, hs, as12, conv_as,
                                                conv_as + 5 * (size_t)HID, NQ);

    // K3: ad1 matvec + ELL build (low VGPR)
    const int ab = ((size_t)NS * 16 + 255) / 256;
    const int eb = (E + 255) / 256;
    misc_k<<<dim3(ab + eb), dim3(256), 0, stream>>>(srcp, dstp, E, deg, ell, ovf, ovf_cnt,
                                                    x_span, v2, c2, ad1, NS, ab);

    // K4: fused 2-layer GAT + final projection (one wave/row)
    gat_fused_k<<<dim3(((size_t)NS * 64 + 255) / 256), dim3(256), 0, stream>>>(
        deg, ell, ovf, ovf_cnt, ad1, (const float2*)as12, hs, conv_b, wd2 + HID,
        conv_b + 5 * (size_t)HID, out_W, out_b, (float*)d_out, NS);
}

// Round 18
// 81.476 us; speedup vs baseline: 1.1472x; 1.1472x over previous
//
#include <hip/hip_runtime.h>
#include <hip/hip_fp16.h>

#define IN_DIM 256
#define HID 128
#define ELLW 16
#define OVF_CAP 32768

using bf16x8 = __attribute__((ext_vector_type(8))) short;
using f32x4 = __attribute__((ext_vector_type(4))) float;

struct h8 { __half2 a, b, c, d; };  // 16B = 8 halves

__device__ __forceinline__ unsigned short f2bf(float f) {
    unsigned u = __float_as_uint(f);
    u += 0x7fffu + ((u >> 16) & 1u);  // RNE (inputs finite)
    return (unsigned short)(u >> 16);
}

// ---- DPP row_ror rotate-reductions over 16-lane groups (VALU pipe) ----
template <int CTRL>
__device__ __forceinline__ float dpp_rot(float x) {
    return __int_as_float(
        __builtin_amdgcn_update_dpp(0, __float_as_int(x), CTRL, 0xf, 0xf, false));
}
__device__ __forceinline__ float rsum16(float x) {
    x += dpp_rot<0x121>(x);
    x += dpp_rot<0x122>(x);
    x += dpp_rot<0x124>(x);
    x += dpp_rot<0x128>(x);
    return x;
}
__device__ __forceinline__ float rmax16(float x) {
    x = fmaxf(x, dpp_rot<0x121>(x));
    x = fmaxf(x, dpp_rot<0x122>(x));
    x = fmaxf(x, dpp_rot<0x124>(x));
    x = fmaxf(x, dpp_rot<0x128>(x));
    return x;
}

__device__ __forceinline__ float lrelu(float t) { return t > 0.f ? t : 0.2f * t; }

__device__ __forceinline__ void accum8(f32x4& a0, f32x4& a1, float a, const h8& hv) {
    const float2 f0 = __half22float2(hv.a);
    const float2 f1 = __half22float2(hv.b);
    const float2 f2 = __half22float2(hv.c);
    const float2 f3 = __half22float2(hv.d);
    a0[0] += a * f0.x; a0[1] += a * f0.y;
    a0[2] += a * f1.x; a0[3] += a * f1.y;
    a1[0] += a * f2.x; a1[1] += a * f2.y;
    a1[2] += a * f3.x; a1[3] += a * f3.y;
}

// epilogue: q = rsum16( relu(acc+bias)·dvec )  (16-lane-group feature dot)
__device__ __forceinline__ float epilogue16(const f32x4& a0, const f32x4& a1,
                                            const float* __restrict__ bias,
                                            const float* __restrict__ dvec, int sl) {
    const f32x4 bb0 = *reinterpret_cast<const f32x4*>(bias + sl * 8);
    const f32x4 bb1 = *reinterpret_cast<const f32x4*>(bias + sl * 8 + 4);
    const f32x4 d0 = *reinterpret_cast<const f32x4*>(dvec + sl * 8);
    const f32x4 d1 = *reinterpret_cast<const f32x4*>(dvec + sl * 8 + 4);
    float q = 0.f;
#pragma unroll
    for (int i = 0; i < 4; ++i) {
        q += fmaxf(a0[i] + bb0[i], 0.f) * d0[i];
        q += fmaxf(a1[i] + bb1[i], 0.f) * d1[i];
    }
    return rsum16(q);
}

// ====== K1: setup: collapsed weights (linW0@Wc_l) + bcomb + wd/v2/c2 + deg zero ======
__global__ __launch_bounds__(256) void setup_k(const float* __restrict__ lin_W,
                                               const float* __restrict__ lin_b,
                                               const float* __restrict__ conv_Ws,
                                               const float* __restrict__ Wd,
                                               const float* __restrict__ adv,
                                               short* __restrict__ wt0,
                                               short* __restrict__ wt1,
                                               float* __restrict__ bc,   // [2][128]
                                               float* __restrict__ wd_out,
                                               float* __restrict__ v2,
                                               float* __restrict__ c2,
                                               int* __restrict__ deg,
                                               int* __restrict__ ovf_cnt, int NS) {
    const int b = blockIdx.x;
    if (b < 256) {
        // Wcomb[l][k][n] = sum_m linW0[k][m] * Wc_l[m][n]; store bf16 ELL-layout
        const int idx = b * 256 + threadIdx.x;  // [0, 65536)
        const int l = idx >> 15;
        const int rem = idx & 32767;
        const int k = rem >> 7;
        const int n = rem & 127;
        const float* lw = lin_W + (size_t)k * HID;
        const float* cw = conv_Ws + (size_t)(l * 5) * HID * HID + n;
        float s = 0.f;
#pragma unroll 4
        for (int m = 0; m < HID; ++m) s += lw[m] * cw[(size_t)m * HID];
        short* wt = l ? wt1 : wt0;
        wt[((k >> 3) << 10) + (n << 3) + (k & 7)] = (short)f2bf(s);
    } else if (b == 256) {
        // bcomb[l][n] = sum_m lin_b0[m] * Wc_l[m][n]
        const int t = threadIdx.x;
        const int l = t >> 7;
        const int n = t & 127;
        const float* cw = conv_Ws + (size_t)(l * 5) * HID * HID + n;
        float s = 0.f;
#pragma unroll 4
        for (int m = 0; m < HID; ++m) s += lin_b[m] * cw[(size_t)m * HID];
        bc[t] = s;
        if (t == 0) ovf_cnt[0] = 0;
    } else if (b == 257) {
        __shared__ float wd1s[HID];
        const int t = threadIdx.x;
        const int l = t >> 7, j = t & 127;
        const float* w = Wd + ((size_t)(l * 5) * HID + j) * HID;
        const float* a = adv + (size_t)(l * 5) * HID;
        float s = 0.f;
        for (int k = 0; k < HID; k += 4) {
            const float4 wv = *reinterpret_cast<const float4*>(w + k);
            const float4 av = *reinterpret_cast<const float4*>(a + k);
            s += wv.x * av.x + wv.y * av.y + wv.z * av.z + wv.w * av.w;
        }
        wd_out[t] = s;
        if (l == 0) wd1s[j] = s;
        __syncthreads();
        const float* wr = lin_W + 2 * (size_t)IN_DIM * HID + (size_t)t * HID;
        float p = 0.f;
        for (int k = 0; k < HID; k += 4) {
            const float4 wv = *reinterpret_cast<const float4*>(wr + k);
            p += wv.x * wd1s[k] + wv.y * wd1s[k + 1] + wv.z * wd1s[k + 2] +
                 wv.w * wd1s[k + 3];
        }
        v2[t] = p;
        if (t == 0) {
            const float* br = lin_b + 2 * HID;
            float q = 0.f;
            for (int k = 0; k < HID; ++k) q += br[k] * wd1s[k];
            c2[0] = q;
        }
    } else {
        const int i4 = ((b - 258) * 256 + threadIdx.x) * 4;
        if (i4 + 4 <= NS) {
            *reinterpret_cast<int4*>(deg + i4) = make_int4(0, 0, 0, 0);
        } else {
            for (int i = i4; i < NS; ++i) deg[i] = 0;
        }
    }
}

// ====== K2: merged per-layer GEMMs + ad1 matvec + ELL build ======
// block order: [0,gb2) GEMM (layer = bid&1), [gb2,gb2+ab) ad1, rest ELL.
// hs layout (half idx): row*256 + j*32 + (m16>>3)*16 + l*8 + (m16&7)
__global__ __launch_bounds__(256) void build_gemm_k(
    const int* __restrict__ src, const int* __restrict__ dst, int E,
    int* __restrict__ deg, int* __restrict__ ell, int2* __restrict__ ovf,
    int* __restrict__ ovf_cnt, const float* __restrict__ A,
    const short* __restrict__ Wt0, const short* __restrict__ Wt1,
    const float* __restrict__ bc, __half* __restrict__ hs,
    float* __restrict__ as12,  // float2-interleaved: [row].{x=as1,y=as2}
    const float* __restrict__ a1v, const float* __restrict__ a2v, int N,
    const float* __restrict__ x_span, const float* __restrict__ v2,
    const float* __restrict__ c2, float* __restrict__ ad1_out, int NS, int gb2,
    int ab) {
    const int b = (int)blockIdx.x;
    if (b < gb2) {
        // ---- per-layer GEMM: 64 rows x 128 cols, acc[8] (low VGPR) ----
        const int l = b & 1;
        const int bid = b >> 1;
        const short* Wt = l ? Wt1 : Wt0;
        const float* av = l ? a2v : a1v;
        const int tid = threadIdx.x;
        const int w = tid >> 6;
        const int lane = tid & 63;
        const int m16 = lane & 15;
        const int kg = lane >> 4;

        const int arow = bid * 64 + w * 16 + m16;
        const bool ok = arow < N;

        f32x4 acc[8];
#pragma unroll
        for (int j = 0; j < 8; ++j) acc[j] = (f32x4){0.f, 0.f, 0.f, 0.f};

        for (int k0 = 0; k0 < IN_DIM; k0 += 32) {
            bf16x8 af = {0, 0, 0, 0, 0, 0, 0, 0};
            if (ok) {
                const float* ap = A + (size_t)arow * IN_DIM + k0 + kg * 8;
                const float4 f0 = *reinterpret_cast<const float4*>(ap);
                const float4 f1 = *reinterpret_cast<const float4*>(ap + 4);
                af[0] = (short)f2bf(f0.x); af[1] = (short)f2bf(f0.y);
                af[2] = (short)f2bf(f0.z); af[3] = (short)f2bf(f0.w);
                af[4] = (short)f2bf(f1.x); af[5] = (short)f2bf(f1.y);
                af[6] = (short)f2bf(f1.z); af[7] = (short)f2bf(f1.w);
            }
            const short* bbase = Wt + (((k0 >> 3) + kg) << 10);
#pragma unroll
            for (int j = 0; j < 8; ++j) {
                const bf16x8 bf =
                    *reinterpret_cast<const bf16x8*>(bbase + ((j * 16 + m16) << 3));
                acc[j] = __builtin_amdgcn_mfma_f32_16x16x32_bf16(af, bf, acc[j], 0, 0, 0);
            }
        }

        const int rbase = bid * 64 + w * 16 + kg * 4;
        float p[4] = {0.f, 0.f, 0.f, 0.f};
#pragma unroll
        for (int j = 0; j < 8; ++j) {
            const int col = j * 16 + m16;
            const float bv = bc[l * 128 + col];
            const float a = av[col];
            const int so = j * 32 + ((m16 >> 3) << 4) + (m16 & 7) + l * 8;
#pragma unroll
            for (int r = 0; r < 4; ++r) {
                const int row = rbase + r;
                const float v = acc[j][r] + bv;
                if (row < N) hs[(size_t)row * 256 + so] = __float2half(v);
                p[r] += v * a;
            }
        }
#pragma unroll
        for (int r = 0; r < 4; ++r) p[r] = rsum16(p[r]);
        if (m16 == 0)
#pragma unroll
            for (int r = 0; r < 4; ++r) {
                const int row = rbase + r;
                if (row < N) as12[2 * (size_t)row + l] = p[r];
            }
        return;
    }
    if (b < gb2 + ab) {
        // ---- ad1 matvec: 16 lanes per SPAN row, streaming x_span once ----
        const int idx = (b - gb2) * 256 + threadIdx.x;
        const int row = idx >> 4;
        const int sl = threadIdx.x & 15;
        if (row >= NS) return;
        const float* xr = x_span + (size_t)row * IN_DIM + sl * 16;
        const float* vr = v2 + sl * 16;
        float p = 0.f;
#pragma unroll
        for (int i = 0; i < 4; ++i) {
            const float4 xv = *reinterpret_cast<const float4*>(xr + i * 4);
            const float4 vv = *reinterpret_cast<const float4*>(vr + i * 4);
            p += xv.x * vv.x + xv.y * vv.y + xv.z * vv.z + xv.w * vv.w;
        }
        p = rsum16(p);
        if (sl == 0) ad1_out[row] = p + c2[0];
        return;
    }
    // ---- ELL build (edge-parallel) ----
    const int e = (b - gb2 - ab) * 256 + threadIdx.x;
    if (e < E) {
        const int d = dst[e], s = src[e];
        const int pos = atomicAdd(deg + d, 1);
        if (pos < ELLW) {
            ell[(size_t)d * ELLW + pos] = s;
        } else {
            const int oi = atomicAdd(ovf_cnt, 1);
            if (oi < OVF_CAP) ovf[oi] = make_int2(d, s);
        }
    }
}

// ====== K3: fused 2-layer GAT — ONE WAVE PER ROW, 4 edges per round ======
__global__ __launch_bounds__(256, 4) void gat_fused_k(
    const int* __restrict__ deg_arr, const int* __restrict__ ell,
    const int2* __restrict__ ovf, const int* __restrict__ ovf_cnt_p,
    const float* __restrict__ ad1_arr, const float2* __restrict__ as12,
    const __half* __restrict__ hs, const float* __restrict__ b1,
    const float* __restrict__ wd2v, const float* __restrict__ b2,
    const float* __restrict__ outW, const float* __restrict__ outb,
    float* __restrict__ out, int Ndst) {
    const int row = (blockIdx.x * blockDim.x + threadIdx.x) >> 6;
    const int lane = threadIdx.x & 63;
    const int sl = lane & 15;
    const int eg = lane >> 4;
    if (row >= Ndst) return;  // wave-uniform

    const int deg = deg_arr[row];
    int ce = ell[(size_t)row * ELLW + sl];
    if (sl >= deg) ce = 0;  // clamp: ELL not zero-initialized beyond deg
    const float2 asv = as12[ce];
    const float ad1 = ad1_arr[row];

    if (deg <= ELLW) {
        // ===== layer-1 softmax (no max-shift; |score| small, exp safe) =====
        const float ex1 = (sl < deg) ? __expf(lrelu(asv.x + ad1)) : 0.f;
        const float al1 = ex1 / (rsum16(ex1) + 1e-16f);

        // ===== gather: 4 edges/round, both layers in one 32B lane-read =====
        f32x4 a0 = {0.f, 0.f, 0.f, 0.f}, a1 = {0.f, 0.f, 0.f, 0.f};
        h8 h2s[4];
#pragma unroll
        for (int r = 0; r < 4; ++r) {
            if (r * 4 < deg) {
                const int e = r * 4 + eg;               // 0..15
                const int s = __shfl(ce, e, 64);        // edge e's src (from lane e)
                const float a = __shfl(al1, e, 64);     // 0 for e >= deg
                const __half* hb = hs + (size_t)s * 256 + sl * 16;
                const h8 hv1 = *reinterpret_cast<const h8*>(hb);
                h2s[r] = *reinterpret_cast<const h8*>(hb + 8);
                accum8(a0, a1, a, hv1);
            }
        }
#pragma unroll
        for (int i = 0; i < 4; ++i) {
            a0[i] += __shfl_xor(a0[i], 16, 64);
            a0[i] += __shfl_xor(a0[i], 32, 64);
            a1[i] += __shfl_xor(a1[i], 16, 64);
            a1[i] += __shfl_xor(a1[i], 32, 64);
        }
        const float ad2 = epilogue16(a0, a1, b1, wd2v, sl);

        // ===== layer 2 (h2 already in registers) =====
        const float ex2 = (sl < deg) ? __expf(lrelu(asv.y + ad2)) : 0.f;
        const float al2 = ex2 / (rsum16(ex2) + 1e-16f);

        f32x4 b0 = {0.f, 0.f, 0.f, 0.f}, b1v = {0.f, 0.f, 0.f, 0.f};
#pragma unroll
        for (int r = 0; r < 4; ++r) {
            if (r * 4 < deg) {
                const float a = __shfl(al2, r * 4 + eg, 64);
                accum8(b0, b1v, a, h2s[r]);
            }
        }
#pragma unroll
        for (int i = 0; i < 4; ++i) {
            b0[i] += __shfl_xor(b0[i], 16, 64);
            b0[i] += __shfl_xor(b0[i], 32, 64);
            b1v[i] += __shfl_xor(b1v[i], 16, 64);
            b1v[i] += __shfl_xor(b1v[i], 32, 64);
        }
        const float q = epilogue16(b0, b1v, b2, outW, sl);
        if (lane == 0) out[row] = q + outb[0];
    } else {
        // ===== general path (deg > 16, ~1e-4 of rows): eg==0 accumulates =====
        int oc = *ovf_cnt_p;
        if (oc > OVF_CAP) oc = OVF_CAP;
        float ad = ad1;
#pragma unroll
        for (int layer = 0; layer < 2; ++layer) {
            const float ac = layer ? asv.y : asv.x;
            const int ho = layer ? 8 : 0;
            const float* bias = layer ? b2 : b1;
            const float* dvec = layer ? outW : wd2v;

            float te = lrelu(ac + ad);
            float m = rmax16(te);
            for (int i = 0; i < oc; ++i) {
                const int2 o = ovf[i];
                if (o.x == row) {
                    const float2 oas = as12[o.y];
                    m = fmaxf(m, lrelu((layer ? oas.y : oas.x) + ad));
                }
            }
            const float ex = __expf(te - m);
            float dsum = rsum16(ex);
            for (int i = 0; i < oc; ++i) {
                const int2 o = ovf[i];
                if (o.x == row) {
                    const float2 oas = as12[o.y];
                    dsum += __expf(lrelu((layer ? oas.y : oas.x) + ad) - m);
                }
            }
            const float inv = 1.f / (dsum + 1e-16f);
            const float al = ex * inv;

            f32x4 acc0 = {0.f, 0.f, 0.f, 0.f}, acc1 = {0.f, 0.f, 0.f, 0.f};
            for (int i = 0; i < 16; ++i) {
                const int s = __shfl(ce, i, 64);
                float a = __shfl(al, i, 64);
                if (eg != 0) a = 0.f;
                const h8 hv =
                    *reinterpret_cast<const h8*>(hs + (size_t)s * 256 + sl * 16 + ho);
                accum8(acc0, acc1, a, hv);
            }
            for (int i = 0; i < oc; ++i) {
                const int2 o = ovf[i];
                if (o.x == row && eg == 0) {
                    const float2 oas = as12[o.y];
                    const float a = __expf(lrelu((layer ? oas.y : oas.x) + ad) - m) * inv;
                    const h8 hv =
                        *reinterpret_cast<const h8*>(hs + (size_t)o.y * 256 + sl * 16 + ho);
                    accum8(acc0, acc1, a, hv);
                }
            }
#pragma unroll
            for (int i = 0; i < 4; ++i) {
                acc0[i] += __shfl_xor(acc0[i], 16, 64);
                acc0[i] += __shfl_xor(acc0[i], 32, 64);
                acc1[i] += __shfl_xor(acc1[i], 16, 64);
                acc1[i] += __shfl_xor(acc1[i], 32, 64);
            }
            const float q = epilogue16(acc0, acc1, bias, dvec, sl);
            if (layer == 0) {
                ad = q;
            } else if (lane == 0) {
                out[row] = q + outb[0];
            }
        }
    }
}

extern "C" void kernel_launch(void* const* d_in, const int* in_sizes, int n_in,
                              void* d_out, int out_size, void* d_ws, size_t ws_size,
                              hipStream_t stream) {
    // Live dataflow: out = relu(gat2)·outW + outb over QENT->SPAN only (see R4/R5).
    const float* x_qent = (const float*)d_in[0];
    const float* x_span = (const float*)d_in[2];
    const int* e_qs = (const int*)d_in[4];  // [2][E]
    const float* lin_W = (const float*)d_in[9];
    const float* lin_b = (const float*)d_in[10];
    const float* conv_Ws = (const float*)d_in[11];
    const float* conv_Wd = (const float*)d_in[12];
    const float* conv_as = (const float*)d_in[13];
    const float* conv_ad = (const float*)d_in[14];
    const float* conv_b = (const float*)d_in[15];
    const float* out_W = (const float*)d_in[16];
    const float* out_b = (const float*)d_in[17];

    const int NQ = in_sizes[0] / IN_DIM;
    const int NS = in_sizes[2] / IN_DIM;
    const int E = in_sizes[4] / 2;
    const int* srcp = e_qs;
    const int* dstp = e_qs + E;
    (void)n_in; (void)out_size;

    // ---- workspace carve (16B-aligned slots) ----
    float* ws = (float*)d_ws;
    size_t off = 0;
    auto alloc = [&](size_t n) {
        n = (n + 3) & ~(size_t)3;
        float* p = ws + off;
        off += n;
        return p;
    };
    __half* hs = (__half*)alloc((size_t)NQ * 128);  // fp16 [NQ][256], layer-interleaved
    float* as12 = alloc(2 * (size_t)NQ);            // float2-interleaved {as1,as2}
    float* ad1 = alloc(NS);
    float* wd2 = alloc(2 * HID);
    float* v2 = alloc(IN_DIM);
    float* c2 = alloc(1);
    float* bc = alloc(2 * HID);
    int* deg = (int*)alloc(NS);
    int* ell = (int*)alloc((size_t)NS * ELLW);
    int2* ovf = (int2*)alloc(2 * OVF_CAP);
    int* ovf_cnt = (int*)alloc(1);
    short* wt0 = (short*)alloc(IN_DIM * HID / 2);
    short* wt1 = (short*)alloc(IN_DIM * HID / 2);
    (void)ws_size;

    // K1: setup (collapsed weights + bcomb + wd/v2/c2 + zero deg/ovf_cnt)
    const int zd = (NS + 1023) / 1024;
    setup_k<<<dim3(258 + zd), dim3(256), 0, stream>>>(
        lin_W, lin_b, conv_Ws, conv_Wd, conv_ad, wt0, wt1, bc, wd2, v2, c2, deg, ovf_cnt,
        NS);

    // K2: per-layer GEMMs (2x blocks, low VGPR) + ad1 matvec + ELL build, merged
    const int gb2 = 2 * ((NQ + 63) / 64);
    const int ab = ((size_t)NS * 16 + 255) / 256;
    const int eb = (E + 255) / 256;
    build_gemm_k<<<dim3(gb2 + ab + eb), dim3(256), 0, stream>>>(
        srcp, dstp, E, deg, ell, ovf, ovf_cnt, x_qent, wt0, wt1, bc, hs, as12, conv_as,
        conv_as + 5 * (size_t)HID, NQ, x_span, v2, c2, ad1, NS, gb2, ab);

    // K3: fused 2-layer GAT + final projection (ONE WAVE PER ROW)
    gat_fused_k<<<dim3(((size_t)NS * 64 + 255) / 256), dim3(256), 0, stream>>>(
        deg, ell, ovf, ovf_cnt, ad1, (const float2*)as12, hs, conv_b, wd2 + HID,
        conv_b + 5 * (size_t)HID, out_W, out_b, (float*)d_out, NS);
}